// Round 11
// baseline (1331.315 us; speedup 1.0000x reference)
//
#include <hip/hip_runtime.h>
#include <hip/hip_bf16.h>

#define NB 16
#define NP 4096
#define MS 1024
#define NN 65536
#define FIN 64
#define FOUT 128
#define KNN_MARGIN 0.25f

typedef __attribute__((ext_vector_type(8))) short short8;
typedef __attribute__((ext_vector_type(4))) float f32x4;
typedef __attribute__((ext_vector_type(2))) float f32x2;

// DPP cumulative-max step on a (dist,idx) key, using v_max_f64.
// Keys are positive f64 bit patterns (finite f32 dist in high word => never NaN),
// so IEEE fmax == unsigned 64-bit max. Invalid DPP lanes -> 0.0 (identity).
template <int CTRL>
__device__ __forceinline__ unsigned long long dpp_fmax_step(unsigned long long k) {
    unsigned lo = (unsigned)k, hi = (unsigned)(k >> 32);
    unsigned plo = (unsigned)__builtin_amdgcn_update_dpp(0, (int)lo, CTRL, 0xf, 0xf, true);
    unsigned phi = (unsigned)__builtin_amdgcn_update_dpp(0, (int)hi, CTRL, 0xf, 0xf, true);
    unsigned long long pk = ((unsigned long long)phi << 32) | plo;
    double a = __builtin_bit_cast(double, k);
    double p = __builtin_bit_cast(double, pk);
    return __builtin_bit_cast(unsigned long long, fmax(a, p));
}

__device__ __forceinline__ unsigned short bf16_rn(float v) {
    unsigned u = __float_as_uint(v);
    unsigned r = u + 0x7FFF + ((u >> 16) & 1);
    return (unsigned short)(r >> 16);
}

// ---------------------------------------------------------------- split: xnorm + bf16 hi/lo (mega's knn input)
__global__ __launch_bounds__(512, 1) void split_kernel(
        const float* __restrict__ feat, float* __restrict__ xnorm,
        unsigned short* __restrict__ Xhi, unsigned short* __restrict__ Xlo) {
    int r = blockIdx.x * 512 + threadIdx.x;
    const float4* fr = (const float4*)&feat[(size_t)r * FIN];
    unsigned short hrow[64], lrow[64];
    float s = 0.f;
#pragma unroll
    for (int i = 0; i < 16; i++) {
        float4 v = fr[i];
        s += v.x * v.x + v.y * v.y + v.z * v.z + v.w * v.w;
        float vv[4] = {v.x, v.y, v.z, v.w};
#pragma unroll
        for (int j = 0; j < 4; j++) {
            unsigned short h = bf16_rn(vv[j]);
            float hf = __uint_as_float((unsigned)h << 16);
            hrow[4 * i + j] = h;
            lrow[4 * i + j] = bf16_rn(vv[j] - hf);
        }
    }
    xnorm[r] = s;
#pragma unroll
    for (int i = 0; i < 8; i++) {
        short8 hv, lv;
#pragma unroll
        for (int j = 0; j < 8; j++) { hv[j] = (short)hrow[8 * i + j]; lv[j] = (short)lrow[8 * i + j]; }
        *(short8*)&Xhi[(size_t)r * 64 + 8 * i] = hv;
        *(short8*)&Xlo[(size_t)r * 64 + 8 * i] = lv;
    }
}

// ---------------------------------------------------------------- mega: FPS (16) || GEMM (256) || knn-all (1024)
// knn-all computes candidates for ALL 4096 rows per cloud (no fps_idx dependency),
// so it executes in the idle-CU shadow of the 585us FPS blocks. LDS request 90112B
// forces 1 block/CU -> FPS blocks run uncontended. Refine later picks the FPS rows.
#define KNN_LOAD(SLOT_H0, SLOT_H1, SLOT_L0, SLOT_L1, SLOT_XN, TILE)                     \
    {                                                                                   \
        const int pr_ = cbase + pstart + (TILE) * 16 + col;                             \
        const unsigned short* Bh_ = Xhi + (size_t)pr_ * 64;                             \
        const unsigned short* Bl_ = Xlo + (size_t)pr_ * 64;                             \
        SLOT_H0 = *(const short8*)(Bh_ + quad * 8);                                     \
        SLOT_H1 = *(const short8*)(Bh_ + 32 + quad * 8);                                \
        SLOT_L0 = *(const short8*)(Bl_ + quad * 8);                                     \
        SLOT_L1 = *(const short8*)(Bl_ + 32 + quad * 8);                                \
        SLOT_XN = xnorm[pr_];                                                           \
    }

#define KNN_MFMA(ACC, H0, H1, L0, L1)                                                   \
    ACC = __builtin_amdgcn_mfma_f32_16x16x32_bf16(Ah0, H0, ACC, 0, 0, 0);               \
    ACC = __builtin_amdgcn_mfma_f32_16x16x32_bf16(Ah1, H1, ACC, 0, 0, 0);               \
    ACC = __builtin_amdgcn_mfma_f32_16x16x32_bf16(Al0, H0, ACC, 0, 0, 0);               \
    ACC = __builtin_amdgcn_mfma_f32_16x16x32_bf16(Al1, H1, ACC, 0, 0, 0);               \
    ACC = __builtin_amdgcn_mfma_f32_16x16x32_bf16(Ah0, L0, ACC, 0, 0, 0);               \
    ACC = __builtin_amdgcn_mfma_f32_16x16x32_bf16(Ah1, L1, ACC, 0, 0, 0);

__global__ __launch_bounds__(512, 1) void mega_kernel(
        const float* __restrict__ pos, const float* __restrict__ feat,
        const float* __restrict__ W, const float* __restrict__ bias,
        int* __restrict__ fps_idx, float* __restrict__ out_pos, float* __restrict__ out_batch,
        const float* __restrict__ xnorm,
        const unsigned short* __restrict__ Xhi, const unsigned short* __restrict__ Xlo,
        __hip_bfloat16* __restrict__ hout, float* __restrict__ gsum, float* __restrict__ gsq,
        unsigned short* __restrict__ cand) {
    // 90112 B LDS -> 1 block/CU (163840/90112 = 1): FPS blocks get a CU alone.
    __shared__ __align__(16) char smraw[90112];
    const int t = threadIdx.x;
    const int b = blockIdx.x;
    if (b < 16) {
        // ---------------- FPS: 512 threads x 8 pts/thread (4 x f32x2 packed pairs)
        float4* plds4 = (float4*)smraw;
        float*  plin  = (float*)smraw;                    // linear staging view
        int* idxL = (int*)(smraw + 65536);
        double* wk = (double*)(smraw + 65536 + 4096);     // [2][8] per-wave keys (16B aligned)
        const float* pb = pos + (size_t)b * NP * 3;
#pragma unroll
        for (int i = 0; i < 24; i++) { int id = t + 512 * i; plin[id] = pb[id]; }
        __syncthreads();
        f32x2 px2[4], py2[4], pz2[4], dist2[4];
#pragma unroll
        for (int j = 0; j < 4; j++) {
            int p0 = t + 512 * (2 * j), p1 = p0 + 512;
            px2[j] = {plin[p0 * 3 + 0], plin[p1 * 3 + 0]};
            py2[j] = {plin[p0 * 3 + 1], plin[p1 * 3 + 1]};
            pz2[j] = {plin[p0 * 3 + 2], plin[p1 * 3 + 2]};
            dist2[j] = {INFINITY, INFINITY};
        }
        __syncthreads();   // all linear reads done before float4 overwrite
#pragma unroll
        for (int j = 0; j < 4; j++) {
            plds4[t + 512 * (2 * j)]     = (float4){px2[j][0], py2[j][0], pz2[j][0], 0.f};
            plds4[t + 512 * (2 * j + 1)] = (float4){px2[j][1], py2[j][1], pz2[j][1], 0.f};
        }
        if (t == 0) idxL[0] = 0;
        __syncthreads();
        float4 c0 = plds4[0];
        float lx = c0.x, ly = c0.y, lz = c0.z;
        const int ln = t & 63, wv = t >> 6;   // 8 waves
        for (int m = 1; m < MS; m++) {
#pragma unroll
            for (int j = 0; j < 4; j++) {
                f32x2 dx = px2[j] - lx, dy = py2[j] - ly, dz = pz2[j] - lz;
                f32x2 d = dx * dx + dy * dy + dz * dz;
                dist2[j] = __builtin_elementwise_min(dist2[j], d);
            }
            float d1[4]; int i1[4];
#pragma unroll
            for (int j = 0; j < 4; j++) {
                bool g = dist2[j][1] > dist2[j][0];
                d1[j] = g ? dist2[j][1] : dist2[j][0];
                i1[j] = 2 * j + (g ? 1 : 0);
            }
            float d2[2]; int i2[2];
#pragma unroll
            for (int j = 0; j < 2; j++) {
                bool g = d1[j + 2] > d1[j];
                d2[j] = g ? d1[j + 2] : d1[j]; i2[j] = g ? i1[j + 2] : i1[j];
            }
            bool g3 = d2[1] > d2[0];
            float bd = g3 ? d2[1] : d2[0];
            int bi = g3 ? i2[1] : i2[0];
            int bp = t + (bi << 9);
            unsigned long long key =
                ((unsigned long long)__float_as_uint(bd) << 32) | (unsigned)(~bp);
            key = dpp_fmax_step<0x111>(key);   // row_shr:1
            key = dpp_fmax_step<0x112>(key);   // row_shr:2
            key = dpp_fmax_step<0x114>(key);   // row_shr:4
            key = dpp_fmax_step<0x118>(key);   // row_shr:8
            key = dpp_fmax_step<0x142>(key);   // row_bcast15
            key = dpp_fmax_step<0x143>(key);   // row_bcast31
            const int par = (m & 1) * 8;
            if (ln == 63) wk[par + wv] = __builtin_bit_cast(double, key);
            __syncthreads();
            const double2* wk2 = (const double2*)(wk + par);   // 4 x b128 broadcast reads
            double2 q01 = wk2[0], q23 = wk2[1], q45 = wk2[2], q67 = wk2[3];
            double ka = fmax(q01.x, q01.y), kb = fmax(q23.x, q23.y);
            double kc = fmax(q45.x, q45.y), kd = fmax(q67.x, q67.y);
            ka = fmax(ka, kb);
            kc = fmax(kc, kd);
            unsigned long long kw = __builtin_bit_cast(unsigned long long, fmax(ka, kc));
            bp = (int)(~(unsigned)kw) & 0xFFF;
            float4 c = plds4[bp];                          // one b128 coords read
            lx = c.x; ly = c.y; lz = c.z;
            if (t == 0) idxL[m] = bp;
        }
        __syncthreads();
        for (int m = t; m < MS; m += 512) {
            int ix = idxL[m];
            size_t o = (size_t)b * MS + m;
            fps_idx[o] = ix;
            float4 c = plds4[ix];
            out_pos[o * 3 + 0] = c.x;
            out_pos[o * 3 + 1] = c.y;
            out_pos[o * 3 + 2] = c.z;
            out_batch[o] = (float)b;
        }
    } else if (b < 272) {
        // ---------------- GEMM + BN stats (rows (b-16)*256 .. +255), 512 threads
        float* wt = (float*)smraw;            // [128][68] W^T
        float* fl = (float*)smraw + 8704;     // [64][68] feature tile
#pragma unroll
        for (int it = 0; it < 4; it++) {
            int lid = t + 512 * it;
            int k = lid >> 5, c4 = lid & 31;
            float4 v = *(const float4*)&W[k * FOUT + c4 * 4];
            wt[(c4 * 4 + 0) * 68 + k] = v.x;
            wt[(c4 * 4 + 1) * 68 + k] = v.y;
            wt[(c4 * 4 + 2) * 68 + k] = v.z;
            wt[(c4 * 4 + 3) * 68 + k] = v.w;
        }
        const int rowbase0 = (b - 16) * 256;
        const int rg = t >> 5, cg = t & 31;
        float sums[4] = {0, 0, 0, 0};
        float sqs[4]  = {0, 0, 0, 0};
        for (int sub = 0; sub < 4; sub++) {
            const int rowbase = rowbase0 + sub * 64;
            __syncthreads();
#pragma unroll
            for (int it = 0; it < 2; it++) {
                int lid = t + 512 * it;
                int r = lid >> 4, f4 = lid & 15;
                float4 v = *(const float4*)&feat[(size_t)(rowbase + r) * FIN + f4 * 4];
                *(float4*)&fl[r * 68 + f4 * 4] = v;
            }
            __syncthreads();
            float acc[4][4];
#pragma unroll
            for (int i = 0; i < 4; i++)
#pragma unroll
                for (int j = 0; j < 4; j++) acc[i][j] = 0.f;
#pragma unroll 2
            for (int k4 = 0; k4 < 16; k4++) {
                float4 f4v[4], w4v[4];
#pragma unroll
                for (int i = 0; i < 4; i++) f4v[i] = *(float4*)&fl[(rg * 4 + i) * 68 + k4 * 4];
#pragma unroll
                for (int j = 0; j < 4; j++) w4v[j] = *(float4*)&wt[(cg + 32 * j) * 68 + k4 * 4];
#pragma unroll
                for (int i = 0; i < 4; i++)
#pragma unroll
                    for (int j = 0; j < 4; j++) {
                        acc[i][j] = fmaf(f4v[i].x, w4v[j].x, acc[i][j]);
                        acc[i][j] = fmaf(f4v[i].y, w4v[j].y, acc[i][j]);
                        acc[i][j] = fmaf(f4v[i].z, w4v[j].z, acc[i][j]);
                        acc[i][j] = fmaf(f4v[i].w, w4v[j].w, acc[i][j]);
                    }
            }
#pragma unroll
            for (int j = 0; j < 4; j++) {
                int c = cg + 32 * j;
                float bc = bias[c];
#pragma unroll
                for (int i = 0; i < 4; i++) {
                    float h = acc[i][j] + bc;
                    sums[j] += h; sqs[j] += h * h;
                    hout[(size_t)(rowbase + rg * 4 + i) * FOUT + c] = __float2bfloat16(h);
                }
            }
        }
        __syncthreads();
        float* suml = fl;
        float* sql  = wt;
#pragma unroll
        for (int j = 0; j < 4; j++) {
            suml[rg * FOUT + cg + 32 * j] = sums[j];
            sql[rg * FOUT + cg + 32 * j]  = sqs[j];
        }
        __syncthreads();
        if (t < FOUT) {
            float S = 0.f, Q = 0.f;
#pragma unroll
            for (int r = 0; r < 16; r++) { S += suml[r * FOUT + t]; Q += sql[r * FOUT + t]; }
            atomicAdd(&gsum[t], S);
            atomicAdd(&gsq[t], Q);
        }
    } else {
        // ---------------- knn-all: candidates for ALL rows. 8 waves x 16 queries = 128 q/block.
        // kb in [0,1024): cloud = kb&15, qg = (kb>>4)&31, half = kb>>9.
        float (*TL)[16][32] = (float(*)[16][32])smraw;                        // 16384 B
        float (*TQ)[16]     = (float(*)[16])(smraw + 16384);                  // 512 B
        int   (*cntL)[16]   = (int(*)[16])(smraw + 16896);                    // 512 B
        unsigned short (*buf)[16][64] = (unsigned short(*)[16][64])(smraw + 17408); // 16384 B
        const int kb = b - 272;
        const int cloud = kb & 15, qg = (kb >> 4) & 31, half = kb >> 9;
        const int wave = t >> 6, lane = t & 63;
        const int quad = lane >> 4, col = lane & 15;
        const int cbase = cloud * NP;
        const int qloc = qg * 128 + wave * 16;

        // A fragments: queries ARE rows qloc..qloc+15 (no fps_idx dependency)
        const int qrow = qloc + col;
        const unsigned short* Qh = Xhi + (size_t)(cbase + qrow) * 64;
        const unsigned short* Ql = Xlo + (size_t)(cbase + qrow) * 64;
        short8 Ah0 = *(const short8*)(Qh + quad * 8);
        short8 Ah1 = *(const short8*)(Qh + 32 + quad * 8);
        short8 Al0 = *(const short8*)(Ql + quad * 8);
        short8 Al1 = *(const short8*)(Ql + 32 + quad * 8);

        const int pstart = half * 2048;
        // -------- phase 1: 2-smallest per (lane, r) stream (depth-2 pipeline)
        float mA[4] = {INFINITY, INFINITY, INFINITY, INFINITY};
        float mB[4] = {INFINITY, INFINITY, INFINITY, INFINITY};
        {
            short8 ah0, ah1, al0, al1; float axn;
            short8 bh0, bh1, bl0, bl1; float bxn;
            KNN_LOAD(ah0, ah1, al0, al1, axn, 0)
            KNN_LOAD(bh0, bh1, bl0, bl1, bxn, 1)
            for (int tt = 0; tt < 128; tt += 2) {
                {
                    f32x4 acc = {0.f, 0.f, 0.f, 0.f};
                    KNN_MFMA(acc, ah0, ah1, al0, al1)
                    float xnv = axn;
                    if (tt + 2 < 128) KNN_LOAD(ah0, ah1, al0, al1, axn, tt + 2)
#pragma unroll
                    for (int r = 0; r < 4; r++) {
                        float s = fmaf(-2.0f, acc[r], xnv);
                        float mx = fmaxf(mA[r], s);
                        mA[r] = fminf(mA[r], s);
                        mB[r] = fminf(mB[r], mx);
                    }
                }
                {
                    f32x4 acc = {0.f, 0.f, 0.f, 0.f};
                    KNN_MFMA(acc, bh0, bh1, bl0, bl1)
                    float xnv = bxn;
                    if (tt + 3 < 128) KNN_LOAD(bh0, bh1, bl0, bl1, bxn, tt + 3)
#pragma unroll
                    for (int r = 0; r < 4; r++) {
                        float s = fmaf(-2.0f, acc[r], xnv);
                        float mx = fmaxf(mA[r], s);
                        mA[r] = fminf(mA[r], s);
                        mB[r] = fminf(mB[r], mx);
                    }
                }
            }
        }
        // -------- threshold: T[q] = 16th smallest of 32 collected (wave-local, no barrier)
#pragma unroll
        for (int r = 0; r < 4; r++) {
            TL[wave][quad * 4 + r][col * 2 + 0] = mA[r];
            TL[wave][quad * 4 + r][col * 2 + 1] = mB[r];
        }
        if (lane < 16) cntL[wave][lane] = 0;
        {
            const int q = lane >> 2, j0 = (lane & 3) * 8;
            float v[32];
#pragma unroll
            for (int j = 0; j < 32; j++) v[j] = TL[wave][q][j];
#pragma unroll
            for (int u = 0; u < 8; u++) {
                float vj = TL[wave][q][j0 + u];
                int jj = j0 + u, rank = 0;
#pragma unroll
                for (int k = 0; k < 32; k++)
                    rank += (v[k] < vj || (v[k] == vj && k < jj)) ? 1 : 0;
                if (rank == 15) TQ[wave][q] = vj;
            }
        }
        // -------- phase 2: emit candidates below threshold (depth-2 pipeline)
        float T0 = TQ[wave][quad * 4 + 0] + KNN_MARGIN;
        float T1 = TQ[wave][quad * 4 + 1] + KNN_MARGIN;
        float T2 = TQ[wave][quad * 4 + 2] + KNN_MARGIN;
        float T3 = TQ[wave][quad * 4 + 3] + KNN_MARGIN;
        {
            short8 ah0, ah1, al0, al1; float axn;
            short8 bh0, bh1, bl0, bl1; float bxn;
            KNN_LOAD(ah0, ah1, al0, al1, axn, 0)
            KNN_LOAD(bh0, bh1, bl0, bl1, bxn, 1)
            for (int tt = 0; tt < 128; tt += 2) {
                {
                    f32x4 acc = {0.f, 0.f, 0.f, 0.f};
                    KNN_MFMA(acc, ah0, ah1, al0, al1)
                    float xnv = axn;
                    if (tt + 2 < 128) KNN_LOAD(ah0, ah1, al0, al1, axn, tt + 2)
                    const int pidx = pstart + tt * 16 + col;
                    float s0 = fmaf(-2.0f, acc[0], xnv);
                    float s1 = fmaf(-2.0f, acc[1], xnv);
                    float s2 = fmaf(-2.0f, acc[2], xnv);
                    float s3 = fmaf(-2.0f, acc[3], xnv);
                    if (s0 <= T0) { int p = atomicAdd(&cntL[wave][quad * 4 + 0], 1); if (p < 64) buf[wave][quad * 4 + 0][p] = (unsigned short)pidx; }
                    if (s1 <= T1) { int p = atomicAdd(&cntL[wave][quad * 4 + 1], 1); if (p < 64) buf[wave][quad * 4 + 1][p] = (unsigned short)pidx; }
                    if (s2 <= T2) { int p = atomicAdd(&cntL[wave][quad * 4 + 2], 1); if (p < 64) buf[wave][quad * 4 + 2][p] = (unsigned short)pidx; }
                    if (s3 <= T3) { int p = atomicAdd(&cntL[wave][quad * 4 + 3], 1); if (p < 64) buf[wave][quad * 4 + 3][p] = (unsigned short)pidx; }
                }
                {
                    f32x4 acc = {0.f, 0.f, 0.f, 0.f};
                    KNN_MFMA(acc, bh0, bh1, bl0, bl1)
                    float xnv = bxn;
                    if (tt + 3 < 128) KNN_LOAD(bh0, bh1, bl0, bl1, bxn, tt + 3)
                    const int pidx = pstart + (tt + 1) * 16 + col;
                    float s0 = fmaf(-2.0f, acc[0], xnv);
                    float s1 = fmaf(-2.0f, acc[1], xnv);
                    float s2 = fmaf(-2.0f, acc[2], xnv);
                    float s3 = fmaf(-2.0f, acc[3], xnv);
                    if (s0 <= T0) { int p = atomicAdd(&cntL[wave][quad * 4 + 0], 1); if (p < 64) buf[wave][quad * 4 + 0][p] = (unsigned short)pidx; }
                    if (s1 <= T1) { int p = atomicAdd(&cntL[wave][quad * 4 + 1], 1); if (p < 64) buf[wave][quad * 4 + 1][p] = (unsigned short)pidx; }
                    if (s2 <= T2) { int p = atomicAdd(&cntL[wave][quad * 4 + 2], 1); if (p < 64) buf[wave][quad * 4 + 2][p] = (unsigned short)pidx; }
                    if (s3 <= T3) { int p = atomicAdd(&cntL[wave][quad * 4 + 3], 1); if (p < 64) buf[wave][quad * 4 + 3][p] = (unsigned short)pidx; }
                }
            }
        }
        // -------- dump (coalesced 128B per query row; sentinel-pad)
#pragma unroll
        for (int q = 0; q < 16; q++) {
            int n = cntL[wave][q];
            unsigned short val = (lane < n) ? buf[wave][q][lane] : (unsigned short)0xFFFF;
            cand[(size_t)(cbase + qloc + q) * 128 + half * 64 + lane] = val;
        }
    }
}

// ---------------------------------------------------------------- refine: exact fp32 top-16 + gather/BN/ReLU/maxpool
// block = one query; cand indexed by the query's POINT ROW (cloud*NP + fps_idx[q]).
__global__ __launch_bounds__(256) void refine_kernel(
        const float* __restrict__ feat, const int* __restrict__ fps_idx,
        const float* __restrict__ xnorm, const unsigned short* __restrict__ cand,
        const __hip_bfloat16* __restrict__ h,
        const float* __restrict__ gsum, const float* __restrict__ gsq,
        const float* __restrict__ gamma, const float* __restrict__ beta,
        float* __restrict__ out_feat) {
    __shared__ float qlds[64];
    __shared__ __align__(16) int2 cDI[128];   // (float bits of d, idx) per candidate
    __shared__ int   rankH[128];
    __shared__ int   fIdx[16];
    __shared__ float cf[256];
    __shared__ float pmax[128];
    const int t = threadIdx.x, b = blockIdx.x;
    const int cloud = b & 15, m = b >> 4;          // cloud <-> XCD locality
    const int q = cloud * MS + m;
    const int cbase = cloud * NP;
    const int qr = fps_idx[q];                     // uniform scalar load
    // BN coefs inline (same fp32 ops as original finalize -> bit-identical)
    if (t < 128) {
        float mean = gsum[t] * (1.0f / NN);
        float var  = gsq[t] * (1.0f / NN) - mean * mean;
        float s = rsqrtf(var + 1e-5f) * gamma[t];
        cf[t] = s;
        cf[128 + t] = beta[t] - mean * s;
    }
    if (t < 16) {
        float4 v = ((const float4*)(feat + (size_t)(cbase + qr) * FIN))[t];
        *(float4*)&qlds[t * 4] = v;
    }
    __syncthreads();
    // exact fp32 distance: candidate c = t>>1, half jh = t&1 covers 32 dims
    const int c = t >> 1, jh = t & 1;
    const unsigned short cs = cand[(size_t)(cbase + qr) * 128 + c];
    const bool valid = (cs != 0xFFFF);
    const int cidx = valid ? (int)cs : 0;
    const float4* xr = (const float4*)(feat + (size_t)(cbase + cidx) * FIN) + jh * 8;
    float a0 = 0.f, a1 = 0.f, a2 = 0.f, a3 = 0.f;
#pragma unroll
    for (int i = 0; i < 8; i++) {
        float4 x4 = xr[i];
        a0 = fmaf(qlds[jh * 32 + 4 * i + 0], x4.x, a0);
        a1 = fmaf(qlds[jh * 32 + 4 * i + 1], x4.y, a1);
        a2 = fmaf(qlds[jh * 32 + 4 * i + 2], x4.z, a2);
        a3 = fmaf(qlds[jh * 32 + 4 * i + 3], x4.w, a3);
    }
    float a = (a0 + a1) + (a2 + a3);
    a += __shfl_xor(a, 1);
    if (jh == 0) {
        float dv = valid ? fmaf(-2.0f, a, xnorm[cbase + cidx]) : INFINITY;
        int   iv = valid ? cidx : (65536 + c);   // distinct tiebreak ids for sentinels
        cDI[c] = make_int2(__float_as_int(dv), iv);
    }
    __syncthreads();
    // rank-count among 128 (lex (d, idx)); thread t: candidate t&127, j-half t>>7
    {
        const int c2 = t & 127, jH = t >> 7;
        int2 my = cDI[c2];
        float dv = __int_as_float(my.x);
        int   iv = my.y;
        const int4* cDI4 = (const int4*)cDI;     // 2 candidates per read
        int rank = 0;
        const int base = jH * 32;                // 64 j's = 32 int4 reads
#pragma unroll 8
        for (int k2 = 0; k2 < 32; k2++) {
            int4 p = cDI4[base + k2];
            float d0 = __int_as_float(p.x); int i0 = p.y;
            float d1 = __int_as_float(p.z); int i1 = p.w;
            rank += (d0 < dv || (d0 == dv && i0 < iv)) ? 1 : 0;
            rank += (d1 < dv || (d1 == dv && i1 < iv)) ? 1 : 0;
        }
        if (jH) rankH[c2] = rank;
        __syncthreads();
        if (!jH) {
            rank += rankH[c2];
            if (rank < 16) fIdx[rank] = iv;
        }
    }
    __syncthreads();
    // gather + BN affine + relu + maxpool; k-halves split across thread halves
    {
        const int tc = t & 127, kH = t >> 7;
        const __hip_bfloat16* hb = h + (size_t)cbase * FOUT;
        const float ac = cf[tc], cc = cf[128 + tc];
        float mx = -INFINITY;
#pragma unroll
        for (int k = 0; k < 8; k++) {
            int row = fIdx[kH * 8 + k];
            float hv = __bfloat162float(hb[(size_t)row * FOUT + tc]);
            mx = fmaxf(mx, fmaxf(fmaf(ac, hv, cc), 0.f));
        }
        if (kH) pmax[tc] = mx;
        __syncthreads();
        if (!kH) out_feat[(size_t)q * FOUT + tc] = fmaxf(mx, pmax[tc]);
    }
}

// ---------------------------------------------------------------- launch
extern "C" void kernel_launch(void* const* d_in, const int* in_sizes, int n_in,
                              void* d_out, int out_size, void* d_ws, size_t ws_size,
                              hipStream_t stream) {
    (void)in_sizes; (void)n_in; (void)out_size; (void)ws_size;
    const float* position = (const float*)d_in[0];
    const float* features = (const float*)d_in[1];
    const float* W        = (const float*)d_in[3];
    const float* bias     = (const float*)d_in[4];
    const float* gamma    = (const float*)d_in[5];
    const float* beta     = (const float*)d_in[6];
    float* out = (float*)d_out;

    char* ws = (char*)d_ws;
    int*   fps_idx = (int*)ws;                               // 64 KB
    float* gsum    = (float*)(ws + 65536);                   // 512 B
    float* gsq     = (float*)(ws + 66048);                   // 512 B
    float* xnorm   = (float*)(ws + 67584);                   // 256 KB -> ends 329728
    unsigned short* cand = (unsigned short*)(ws + 329728);   // 16 MB  -> ends 17106944
    unsigned short* Xhi  = (unsigned short*)(ws + 17106944); // 8 MB   -> ends 25495552
    __hip_bfloat16* hbuf = (__hip_bfloat16*)(ws + 25495552); // 16 MB  -> ends ~42.3 MB

    float* out_feat  = out;                 // [16384][128]
    float* out_pos   = out + 2097152;       // [16384][3]
    float* out_batch = out + 2146304;       // [16384]
    // Stash Xlo in the out_feat region (8 MB exact fit); refine overwrites it afterwards.
    unsigned short* Xlo = (unsigned short*)out;

    hipMemsetAsync(gsum, 0, 1024, stream);  // zero gsum+gsq
    split_kernel<<<128, 512, 0, stream>>>(features, xnorm, Xhi, Xlo);
    mega_kernel<<<1296, 512, 0, stream>>>(position, features, W, bias,
                                          fps_idx, out_pos, out_batch, xnorm, Xhi, Xlo,
                                          hbuf, gsum, gsq, cand);
    refine_kernel<<<16384, 256, 0, stream>>>(features, fps_idx, xnorm, cand,
                                             hbuf, gsum, gsq, gamma, beta, out_feat);
}

// Round 12
// 758.956 us; speedup vs baseline: 1.7541x; 1.7541x over previous
//
#include <hip/hip_runtime.h>
#include <hip/hip_bf16.h>

#define NB 16
#define NP 4096
#define MS 1024
#define NN 65536
#define FIN 64
#define FOUT 128
#define KNN_MARGIN 0.25f

typedef __attribute__((ext_vector_type(8))) short short8;
typedef __attribute__((ext_vector_type(4))) float f32x4;
typedef __attribute__((ext_vector_type(2))) float f32x2;

// DPP cumulative-max step on a (dist,idx) key, using v_max_f64.
// Keys are positive f64 bit patterns (finite f32 dist in high word => never NaN),
// so IEEE fmax == unsigned 64-bit max. Invalid DPP lanes -> 0.0 (identity).
template <int CTRL>
__device__ __forceinline__ unsigned long long dpp_fmax_step(unsigned long long k) {
    unsigned lo = (unsigned)k, hi = (unsigned)(k >> 32);
    unsigned plo = (unsigned)__builtin_amdgcn_update_dpp(0, (int)lo, CTRL, 0xf, 0xf, true);
    unsigned phi = (unsigned)__builtin_amdgcn_update_dpp(0, (int)hi, CTRL, 0xf, 0xf, true);
    unsigned long long pk = ((unsigned long long)phi << 32) | plo;
    double a = __builtin_bit_cast(double, k);
    double p = __builtin_bit_cast(double, pk);
    return __builtin_bit_cast(unsigned long long, fmax(a, p));
}

__device__ __forceinline__ unsigned short bf16_rn(float v) {
    unsigned u = __float_as_uint(v);
    unsigned r = u + 0x7FFF + ((u >> 16) & 1);
    return (unsigned short)(r >> 16);
}

// Tiled fragment layout Xt: per 16-point tile, 4 frags x 64 lanes x 8 shorts (4 KB).
//   frag0 = hi[quad*8..+8) of point col   (lane = quad*16+col)
//   frag1 = hi[32+quad*8..+8)
//   frag2 = lo[quad*8..+8)
//   frag3 = lo[32+quad*8..+8)
// knn B-loads: tb + frag*512 + lane*8 -> consecutive lanes read consecutive 16B
// (ONE coalesced 1KB transaction per instruction, vs 16 scattered lines before).

// ---------------------------------------------------------------- front: FPS + GEMM + split(tiled) fused
__global__ __launch_bounds__(512, 1) void front_kernel(
        const float* __restrict__ pos, const float* __restrict__ feat,
        const float* __restrict__ W, const float* __restrict__ bias,
        int* __restrict__ fps_idx, float* __restrict__ out_pos, float* __restrict__ out_batch,
        float* __restrict__ xnorm, unsigned short* __restrict__ Xt,
        __hip_bfloat16* __restrict__ hout, float* __restrict__ gsum, float* __restrict__ gsq) {
    // FPS view: plds4[4096] float4 (65536 B) + idxL[1024] int (4096 B) + wk[2][8] double (128 B)
    __shared__ __align__(16) char smraw[69760];
    const int t = threadIdx.x;
    const int b = blockIdx.x;
    if (b < 16) {
        // ---------------- FPS: 512 threads x 8 pts/thread (4 x f32x2 packed pairs)
        float4* plds4 = (float4*)smraw;
        float*  plin  = (float*)smraw;                    // linear staging view
        int* idxL = (int*)(smraw + 65536);
        double* wk = (double*)(smraw + 65536 + 4096);     // [2][8] per-wave keys (16B aligned)
        const float* pb = pos + (size_t)b * NP * 3;
#pragma unroll
        for (int i = 0; i < 24; i++) { int id = t + 512 * i; plin[id] = pb[id]; }
        __syncthreads();
        f32x2 px2[4], py2[4], pz2[4], dist2[4];
#pragma unroll
        for (int j = 0; j < 4; j++) {
            int p0 = t + 512 * (2 * j), p1 = p0 + 512;
            px2[j] = {plin[p0 * 3 + 0], plin[p1 * 3 + 0]};
            py2[j] = {plin[p0 * 3 + 1], plin[p1 * 3 + 1]};
            pz2[j] = {plin[p0 * 3 + 2], plin[p1 * 3 + 2]};
            dist2[j] = {INFINITY, INFINITY};
        }
        __syncthreads();   // all linear reads done before float4 overwrite
#pragma unroll
        for (int j = 0; j < 4; j++) {
            plds4[t + 512 * (2 * j)]     = (float4){px2[j][0], py2[j][0], pz2[j][0], 0.f};
            plds4[t + 512 * (2 * j + 1)] = (float4){px2[j][1], py2[j][1], pz2[j][1], 0.f};
        }
        if (t == 0) idxL[0] = 0;
        __syncthreads();
        float4 c0 = plds4[0];
        float lx = c0.x, ly = c0.y, lz = c0.z;
        const int ln = t & 63, wv = t >> 6;   // 8 waves
        for (int m = 1; m < MS; m++) {
#pragma unroll
            for (int j = 0; j < 4; j++) {
                f32x2 dx = px2[j] - lx, dy = py2[j] - ly, dz = pz2[j] - lz;
                f32x2 d = dx * dx + dy * dy + dz * dz;
                dist2[j] = __builtin_elementwise_min(dist2[j], d);
            }
            float d1[4]; int i1[4];
#pragma unroll
            for (int j = 0; j < 4; j++) {
                bool g = dist2[j][1] > dist2[j][0];
                d1[j] = g ? dist2[j][1] : dist2[j][0];
                i1[j] = 2 * j + (g ? 1 : 0);
            }
            float d2[2]; int i2[2];
#pragma unroll
            for (int j = 0; j < 2; j++) {
                bool g = d1[j + 2] > d1[j];
                d2[j] = g ? d1[j + 2] : d1[j]; i2[j] = g ? i1[j + 2] : i1[j];
            }
            bool g3 = d2[1] > d2[0];
            float bd = g3 ? d2[1] : d2[0];
            int bi = g3 ? i2[1] : i2[0];
            int bp = t + (bi << 9);
            unsigned long long key =
                ((unsigned long long)__float_as_uint(bd) << 32) | (unsigned)(~bp);
            key = dpp_fmax_step<0x111>(key);   // row_shr:1
            key = dpp_fmax_step<0x112>(key);   // row_shr:2
            key = dpp_fmax_step<0x114>(key);   // row_shr:4
            key = dpp_fmax_step<0x118>(key);   // row_shr:8
            key = dpp_fmax_step<0x142>(key);   // row_bcast15
            key = dpp_fmax_step<0x143>(key);   // row_bcast31
            const int par = (m & 1) * 8;
            if (ln == 63) wk[par + wv] = __builtin_bit_cast(double, key);
            __syncthreads();
            const double2* wk2 = (const double2*)(wk + par);   // 4 x b128 broadcast reads
            double2 q01 = wk2[0], q23 = wk2[1], q45 = wk2[2], q67 = wk2[3];
            double ka = fmax(q01.x, q01.y), kb = fmax(q23.x, q23.y);
            double kc = fmax(q45.x, q45.y), kd = fmax(q67.x, q67.y);
            ka = fmax(ka, kb);
            kc = fmax(kc, kd);
            unsigned long long kw = __builtin_bit_cast(unsigned long long, fmax(ka, kc));
            bp = (int)(~(unsigned)kw) & 0xFFF;
            float4 c = plds4[bp];                          // one b128 coords read
            lx = c.x; ly = c.y; lz = c.z;
            if (t == 0) idxL[m] = bp;
        }
        __syncthreads();
        for (int m = t; m < MS; m += 512) {
            int ix = idxL[m];
            size_t o = (size_t)b * MS + m;
            fps_idx[o] = ix;
            float4 c = plds4[ix];
            out_pos[o * 3 + 0] = c.x;
            out_pos[o * 3 + 1] = c.y;
            out_pos[o * 3 + 2] = c.z;
            out_batch[o] = (float)b;
        }
    } else if (b < 272) {
        // ---------------- GEMM + BN stats (rows (b-16)*256 .. +255), 512 threads
        float* wt = (float*)smraw;            // [128][68] W^T
        float* fl = (float*)smraw + 8704;     // [64][68] feature tile
#pragma unroll
        for (int it = 0; it < 4; it++) {
            int lid = t + 512 * it;
            int k = lid >> 5, c4 = lid & 31;
            float4 v = *(const float4*)&W[k * FOUT + c4 * 4];
            wt[(c4 * 4 + 0) * 68 + k] = v.x;
            wt[(c4 * 4 + 1) * 68 + k] = v.y;
            wt[(c4 * 4 + 2) * 68 + k] = v.z;
            wt[(c4 * 4 + 3) * 68 + k] = v.w;
        }
        const int rowbase0 = (b - 16) * 256;
        const int rg = t >> 5, cg = t & 31;
        float sums[4] = {0, 0, 0, 0};
        float sqs[4]  = {0, 0, 0, 0};
        for (int sub = 0; sub < 4; sub++) {
            const int rowbase = rowbase0 + sub * 64;
            __syncthreads();
#pragma unroll
            for (int it = 0; it < 2; it++) {
                int lid = t + 512 * it;
                int r = lid >> 4, f4 = lid & 15;
                float4 v = *(const float4*)&feat[(size_t)(rowbase + r) * FIN + f4 * 4];
                *(float4*)&fl[r * 68 + f4 * 4] = v;
            }
            __syncthreads();
            float acc[4][4];
#pragma unroll
            for (int i = 0; i < 4; i++)
#pragma unroll
                for (int j = 0; j < 4; j++) acc[i][j] = 0.f;
#pragma unroll 2
            for (int k4 = 0; k4 < 16; k4++) {
                float4 f4v[4], w4v[4];
#pragma unroll
                for (int i = 0; i < 4; i++) f4v[i] = *(float4*)&fl[(rg * 4 + i) * 68 + k4 * 4];
#pragma unroll
                for (int j = 0; j < 4; j++) w4v[j] = *(float4*)&wt[(cg + 32 * j) * 68 + k4 * 4];
#pragma unroll
                for (int i = 0; i < 4; i++)
#pragma unroll
                    for (int j = 0; j < 4; j++) {
                        acc[i][j] = fmaf(f4v[i].x, w4v[j].x, acc[i][j]);
                        acc[i][j] = fmaf(f4v[i].y, w4v[j].y, acc[i][j]);
                        acc[i][j] = fmaf(f4v[i].z, w4v[j].z, acc[i][j]);
                        acc[i][j] = fmaf(f4v[i].w, w4v[j].w, acc[i][j]);
                    }
            }
#pragma unroll
            for (int j = 0; j < 4; j++) {
                int c = cg + 32 * j;
                float bc = bias[c];
#pragma unroll
                for (int i = 0; i < 4; i++) {
                    float h = acc[i][j] + bc;
                    sums[j] += h; sqs[j] += h * h;
                    hout[(size_t)(rowbase + rg * 4 + i) * FOUT + c] = __float2bfloat16(h);
                }
            }
        }
        __syncthreads();
        float* suml = fl;
        float* sql  = wt;
#pragma unroll
        for (int j = 0; j < 4; j++) {
            suml[rg * FOUT + cg + 32 * j] = sums[j];
            sql[rg * FOUT + cg + 32 * j]  = sqs[j];
        }
        __syncthreads();
        if (t < FOUT) {
            float S = 0.f, Q = 0.f;
#pragma unroll
            for (int r = 0; r < 16; r++) { S += suml[r * FOUT + t]; Q += sql[r * FOUT + t]; }
            atomicAdd(&gsum[t], S);
            atomicAdd(&gsq[t], Q);
        }
    } else {
        // ---------------- xnorm + bf16 hi/lo split into TILED layout (128 blocks)
        int r = (b - 272) * 512 + t;          // global point row in [0, 65536)
        const float4* fr = (const float4*)&feat[(size_t)r * FIN];
        unsigned short hrow[64], lrow[64];
        float s = 0.f;
#pragma unroll
        for (int i = 0; i < 16; i++) {
            float4 v = fr[i];
            s += v.x * v.x + v.y * v.y + v.z * v.z + v.w * v.w;
            float vv[4] = {v.x, v.y, v.z, v.w};
#pragma unroll
            for (int j = 0; j < 4; j++) {
                unsigned short h = bf16_rn(vv[j]);
                float hf = __uint_as_float((unsigned)h << 16);
                hrow[4 * i + j] = h;
                lrow[4 * i + j] = bf16_rn(vv[j] - hf);
            }
        }
        xnorm[r] = s;
        const size_t tbase = (size_t)(r >> 4) * 2048;   // shorts
        const int col = r & 15;
#pragma unroll
        for (int q = 0; q < 4; q++) {
            short8 f0, f1, f2, f3;
#pragma unroll
            for (int j = 0; j < 8; j++) {
                f0[j] = (short)hrow[q * 8 + j];
                f1[j] = (short)hrow[32 + q * 8 + j];
                f2[j] = (short)lrow[q * 8 + j];
                f3[j] = (short)lrow[32 + q * 8 + j];
            }
            const int ch = (q * 16 + col) * 8;
            *(short8*)&Xt[tbase + ch]        = f0;
            *(short8*)&Xt[tbase + 512 + ch]  = f1;
            *(short8*)&Xt[tbase + 1024 + ch] = f2;
            *(short8*)&Xt[tbase + 1536 + ch] = f3;
        }
    }
}

// ---------------------------------------------------------------- KNN filter: MFMA + two-phase threshold
// grid 512: cloud(16) x qgroup(16) x half(2). Wave w owns queries qg*64+w*16..+15 vs 2048 points.
// B-side loads fully coalesced via tiled layout; depth-2 register pipeline.
#define KNN_LOAD(SLOT_H0, SLOT_H1, SLOT_L0, SLOT_L1, SLOT_XN, TILE)                     \
    {                                                                                   \
        const unsigned short* tb_ = Xt + (size_t)(gtbase + (TILE)) * 2048;              \
        SLOT_H0 = *(const short8*)(tb_ + lane * 8);                                     \
        SLOT_H1 = *(const short8*)(tb_ + 512 + lane * 8);                               \
        SLOT_L0 = *(const short8*)(tb_ + 1024 + lane * 8);                              \
        SLOT_L1 = *(const short8*)(tb_ + 1536 + lane * 8);                              \
        SLOT_XN = xnorm[cbase + pstart + (TILE) * 16 + col];                            \
    }

#define KNN_MFMA(ACC, H0, H1, L0, L1)                                                   \
    ACC = __builtin_amdgcn_mfma_f32_16x16x32_bf16(Ah0, H0, ACC, 0, 0, 0);               \
    ACC = __builtin_amdgcn_mfma_f32_16x16x32_bf16(Ah1, H1, ACC, 0, 0, 0);               \
    ACC = __builtin_amdgcn_mfma_f32_16x16x32_bf16(Al0, H0, ACC, 0, 0, 0);               \
    ACC = __builtin_amdgcn_mfma_f32_16x16x32_bf16(Al1, H1, ACC, 0, 0, 0);               \
    ACC = __builtin_amdgcn_mfma_f32_16x16x32_bf16(Ah0, L0, ACC, 0, 0, 0);               \
    ACC = __builtin_amdgcn_mfma_f32_16x16x32_bf16(Ah1, L1, ACC, 0, 0, 0);

__global__ __launch_bounds__(256, 2) void knn_kernel(
        const unsigned short* __restrict__ Xt,
        const int* __restrict__ fps_idx, const float* __restrict__ xnorm,
        unsigned short* __restrict__ cand) {
    __shared__ float TL[4][16][32];            // [wave][q][col*2+{0,1}] collected values
    __shared__ float TQ[4][16];                // per-query threshold
    __shared__ int   cntL[4][16];
    __shared__ unsigned short buf[4][16][64];
    const int t = threadIdx.x, b = blockIdx.x;
    const int cloud = b & 15, qg = (b >> 4) & 15, half = b >> 8;
    const int wave = t >> 6, lane = t & 63;
    const int quad = lane >> 4, col = lane & 15;
    const int cbase = cloud * NP;
    const int qloc = qg * 64 + wave * 16;
    const int pstart = half * 2048;
    const int gtbase = cloud * 256 + half * 128;   // global tile base for this half

    // A fragments from tiled layout: lane (quad,col) reads query row fps_idx[..+col]'s chunk quad
    const int qrow = fps_idx[cloud * MS + qloc + col];
    const unsigned short* qt = Xt + (size_t)(cloud * 256 + (qrow >> 4)) * 2048
                               + (size_t)((quad << 4) | (qrow & 15)) * 8;
    short8 Ah0 = *(const short8*)(qt);
    short8 Ah1 = *(const short8*)(qt + 512);
    short8 Al0 = *(const short8*)(qt + 1024);
    short8 Al1 = *(const short8*)(qt + 1536);

    // -------- phase 1: unconditional 2-smallest per (lane, r) stream (depth-2 pipeline)
    float mA[4] = {INFINITY, INFINITY, INFINITY, INFINITY};
    float mB[4] = {INFINITY, INFINITY, INFINITY, INFINITY};
    {
        short8 ah0, ah1, al0, al1; float axn;   // slot A (even tiles)
        short8 bh0, bh1, bl0, bl1; float bxn;   // slot B (odd tiles)
        KNN_LOAD(ah0, ah1, al0, al1, axn, 0)
        KNN_LOAD(bh0, bh1, bl0, bl1, bxn, 1)
        for (int tt = 0; tt < 128; tt += 2) {
            {
                f32x4 acc = {0.f, 0.f, 0.f, 0.f};
                KNN_MFMA(acc, ah0, ah1, al0, al1)
                float xnv = axn;
                if (tt + 2 < 128) KNN_LOAD(ah0, ah1, al0, al1, axn, tt + 2)
#pragma unroll
                for (int r = 0; r < 4; r++) {
                    float s = fmaf(-2.0f, acc[r], xnv);
                    float mx = fmaxf(mA[r], s);
                    mA[r] = fminf(mA[r], s);
                    mB[r] = fminf(mB[r], mx);
                }
            }
            {
                f32x4 acc = {0.f, 0.f, 0.f, 0.f};
                KNN_MFMA(acc, bh0, bh1, bl0, bl1)
                float xnv = bxn;
                if (tt + 3 < 128) KNN_LOAD(bh0, bh1, bl0, bl1, bxn, tt + 3)
#pragma unroll
                for (int r = 0; r < 4; r++) {
                    float s = fmaf(-2.0f, acc[r], xnv);
                    float mx = fmaxf(mA[r], s);
                    mA[r] = fminf(mA[r], s);
                    mB[r] = fminf(mB[r], mx);
                }
            }
        }
    }
    // -------- threshold: T[q] = 16th smallest of {mA,mB over 16 cols} (wave-local LDS, no barrier)
#pragma unroll
    for (int r = 0; r < 4; r++) {
        TL[wave][quad * 4 + r][col * 2 + 0] = mA[r];
        TL[wave][quad * 4 + r][col * 2 + 1] = mB[r];
    }
    if (lane < 16) cntL[wave][lane] = 0;
    {
        const int q = lane >> 2, j0 = (lane & 3) * 8;
        float v[32];
#pragma unroll
        for (int j = 0; j < 32; j++) v[j] = TL[wave][q][j];
#pragma unroll
        for (int u = 0; u < 8; u++) {
            float vj = TL[wave][q][j0 + u];
            int jj = j0 + u, rank = 0;
#pragma unroll
            for (int k = 0; k < 32; k++)
                rank += (v[k] < vj || (v[k] == vj && k < jj)) ? 1 : 0;
            if (rank == 15) TQ[wave][q] = vj;
        }
    }
    // -------- phase 2: emit candidates below threshold (depth-2 pipeline)
    float T0 = TQ[wave][quad * 4 + 0] + KNN_MARGIN;
    float T1 = TQ[wave][quad * 4 + 1] + KNN_MARGIN;
    float T2 = TQ[wave][quad * 4 + 2] + KNN_MARGIN;
    float T3 = TQ[wave][quad * 4 + 3] + KNN_MARGIN;
    {
        short8 ah0, ah1, al0, al1; float axn;
        short8 bh0, bh1, bl0, bl1; float bxn;
        KNN_LOAD(ah0, ah1, al0, al1, axn, 0)
        KNN_LOAD(bh0, bh1, bl0, bl1, bxn, 1)
        for (int tt = 0; tt < 128; tt += 2) {
            {
                f32x4 acc = {0.f, 0.f, 0.f, 0.f};
                KNN_MFMA(acc, ah0, ah1, al0, al1)
                float xnv = axn;
                if (tt + 2 < 128) KNN_LOAD(ah0, ah1, al0, al1, axn, tt + 2)
                const int pidx = pstart + tt * 16 + col;
                float s0 = fmaf(-2.0f, acc[0], xnv);
                float s1 = fmaf(-2.0f, acc[1], xnv);
                float s2 = fmaf(-2.0f, acc[2], xnv);
                float s3 = fmaf(-2.0f, acc[3], xnv);
                if (s0 <= T0) { int p = atomicAdd(&cntL[wave][quad * 4 + 0], 1); if (p < 64) buf[wave][quad * 4 + 0][p] = (unsigned short)pidx; }
                if (s1 <= T1) { int p = atomicAdd(&cntL[wave][quad * 4 + 1], 1); if (p < 64) buf[wave][quad * 4 + 1][p] = (unsigned short)pidx; }
                if (s2 <= T2) { int p = atomicAdd(&cntL[wave][quad * 4 + 2], 1); if (p < 64) buf[wave][quad * 4 + 2][p] = (unsigned short)pidx; }
                if (s3 <= T3) { int p = atomicAdd(&cntL[wave][quad * 4 + 3], 1); if (p < 64) buf[wave][quad * 4 + 3][p] = (unsigned short)pidx; }
            }
            {
                f32x4 acc = {0.f, 0.f, 0.f, 0.f};
                KNN_MFMA(acc, bh0, bh1, bl0, bl1)
                float xnv = bxn;
                if (tt + 3 < 128) KNN_LOAD(bh0, bh1, bl0, bl1, bxn, tt + 3)
                const int pidx = pstart + (tt + 1) * 16 + col;
                float s0 = fmaf(-2.0f, acc[0], xnv);
                float s1 = fmaf(-2.0f, acc[1], xnv);
                float s2 = fmaf(-2.0f, acc[2], xnv);
                float s3 = fmaf(-2.0f, acc[3], xnv);
                if (s0 <= T0) { int p = atomicAdd(&cntL[wave][quad * 4 + 0], 1); if (p < 64) buf[wave][quad * 4 + 0][p] = (unsigned short)pidx; }
                if (s1 <= T1) { int p = atomicAdd(&cntL[wave][quad * 4 + 1], 1); if (p < 64) buf[wave][quad * 4 + 1][p] = (unsigned short)pidx; }
                if (s2 <= T2) { int p = atomicAdd(&cntL[wave][quad * 4 + 2], 1); if (p < 64) buf[wave][quad * 4 + 2][p] = (unsigned short)pidx; }
                if (s3 <= T3) { int p = atomicAdd(&cntL[wave][quad * 4 + 3], 1); if (p < 64) buf[wave][quad * 4 + 3][p] = (unsigned short)pidx; }
            }
        }
    }
    // -------- dump (coalesced 128B per query; sentinel-pad)
#pragma unroll
    for (int q = 0; q < 16; q++) {
        int n = cntL[wave][q];
        unsigned short val = (lane < n) ? buf[wave][q][lane] : (unsigned short)0xFFFF;
        cand[(size_t)(cloud * MS + qloc + q) * 128 + half * 64 + lane] = val;
    }
}

// ---------------------------------------------------------------- refine: exact fp32 top-16 + gather/BN/ReLU/maxpool
// block = one query; 128 candidate slots (sentinel-padded), 2 lanes/candidate.
__global__ __launch_bounds__(256) void refine_kernel(
        const float* __restrict__ feat, const int* __restrict__ fps_idx,
        const float* __restrict__ xnorm, const unsigned short* __restrict__ cand,
        const __hip_bfloat16* __restrict__ h,
        const float* __restrict__ gsum, const float* __restrict__ gsq,
        const float* __restrict__ gamma, const float* __restrict__ beta,
        float* __restrict__ out_feat) {
    __shared__ float qlds[64];
    __shared__ __align__(16) int2 cDI[128];   // (float bits of d, idx) per candidate
    __shared__ int   rankH[128];
    __shared__ int   fIdx[16];
    __shared__ float cf[256];
    __shared__ float pmax[128];
    const int t = threadIdx.x, b = blockIdx.x;
    const int cloud = b & 15, m = b >> 4;          // cloud <-> XCD locality
    const int q = cloud * MS + m;
    const int cbase = cloud * NP;
    // BN coefs inline (same fp32 ops as original finalize -> bit-identical)
    if (t < 128) {
        float mean = gsum[t] * (1.0f / NN);
        float var  = gsq[t] * (1.0f / NN) - mean * mean;
        float s = rsqrtf(var + 1e-5f) * gamma[t];
        cf[t] = s;
        cf[128 + t] = beta[t] - mean * s;
    }
    if (t < 16) {
        int qr = fps_idx[q];
        float4 v = ((const float4*)(feat + (size_t)(cbase + qr) * FIN))[t];
        *(float4*)&qlds[t * 4] = v;
    }
    __syncthreads();
    // exact fp32 distance: candidate c = t>>1, half jh = t&1 covers 32 dims
    const int c = t >> 1, jh = t & 1;
    const unsigned short cs = cand[(size_t)q * 128 + c];
    const bool valid = (cs != 0xFFFF);
    const int cidx = valid ? (int)cs : 0;
    const float4* xr = (const float4*)(feat + (size_t)(cbase + cidx) * FIN) + jh * 8;
    float a0 = 0.f, a1 = 0.f, a2 = 0.f, a3 = 0.f;
#pragma unroll
    for (int i = 0; i < 8; i++) {
        float4 x4 = xr[i];
        a0 = fmaf(qlds[jh * 32 + 4 * i + 0], x4.x, a0);
        a1 = fmaf(qlds[jh * 32 + 4 * i + 1], x4.y, a1);
        a2 = fmaf(qlds[jh * 32 + 4 * i + 2], x4.z, a2);
        a3 = fmaf(qlds[jh * 32 + 4 * i + 3], x4.w, a3);
    }
    float a = (a0 + a1) + (a2 + a3);
    a += __shfl_xor(a, 1);
    if (jh == 0) {
        float dv = valid ? fmaf(-2.0f, a, xnorm[cbase + cidx]) : INFINITY;
        int   iv = valid ? cidx : (65536 + c);   // distinct tiebreak ids for sentinels
        cDI[c] = make_int2(__float_as_int(dv), iv);
    }
    __syncthreads();
    // rank-count among 128 (lex (d, idx)); thread t: candidate t&127, j-half t>>7
    {
        const int c2 = t & 127, jH = t >> 7;
        int2 my = cDI[c2];
        float dv = __int_as_float(my.x);
        int   iv = my.y;
        const int4* cDI4 = (const int4*)cDI;     // 2 candidates per read
        int rank = 0;
        const int base = jH * 32;                // 64 j's = 32 int4 reads
#pragma unroll 8
        for (int k2 = 0; k2 < 32; k2++) {
            int4 p = cDI4[base + k2];
            float d0 = __int_as_float(p.x); int i0 = p.y;
            float d1 = __int_as_float(p.z); int i1 = p.w;
            rank += (d0 < dv || (d0 == dv && i0 < iv)) ? 1 : 0;
            rank += (d1 < dv || (d1 == dv && i1 < iv)) ? 1 : 0;
        }
        if (jH) rankH[c2] = rank;
        __syncthreads();
        if (!jH) {
            rank += rankH[c2];
            if (rank < 16) fIdx[rank] = iv;
        }
    }
    __syncthreads();
    // gather + BN affine + relu + maxpool; k-halves split across thread halves
    {
        const int tc = t & 127, kH = t >> 7;
        const __hip_bfloat16* hb = h + (size_t)cbase * FOUT;
        const float ac = cf[tc], cc = cf[128 + tc];
        float mx = -INFINITY;
#pragma unroll
        for (int k = 0; k < 8; k++) {
            int row = fIdx[kH * 8 + k];
            float hv = __bfloat162float(hb[(size_t)row * FOUT + tc]);
            mx = fmaxf(mx, fmaxf(fmaf(ac, hv, cc), 0.f));
        }
        if (kH) pmax[tc] = mx;
        __syncthreads();
        if (!kH) out_feat[(size_t)q * FOUT + tc] = fmaxf(mx, pmax[tc]);
    }
}

// ---------------------------------------------------------------- launch
extern "C" void kernel_launch(void* const* d_in, const int* in_sizes, int n_in,
                              void* d_out, int out_size, void* d_ws, size_t ws_size,
                              hipStream_t stream) {
    (void)in_sizes; (void)n_in; (void)out_size; (void)ws_size;
    const float* position = (const float*)d_in[0];
    const float* features = (const float*)d_in[1];
    const float* W        = (const float*)d_in[3];
    const float* bias     = (const float*)d_in[4];
    const float* gamma    = (const float*)d_in[5];
    const float* beta     = (const float*)d_in[6];
    float* out = (float*)d_out;

    char* ws = (char*)d_ws;
    int*   fps_idx = (int*)ws;                               // 64 KB
    float* gsum    = (float*)(ws + 65536);                   // 512 B
    float* gsq     = (float*)(ws + 66048);                   // 512 B
    float* xnorm   = (float*)(ws + 67584);                   // 256 KB -> ends 329728
    unsigned short* cand = (unsigned short*)(ws + 329728);   // 4 MB   -> ends 4524032
    unsigned short* Xt   = (unsigned short*)(ws + 4524032);  // 16 MB tiled -> ends 21301248
    __hip_bfloat16* hbuf = (__hip_bfloat16*)(ws + 21301248); // 16 MB  -> ends ~37.3 MB

    float* out_feat  = out;                 // [16384][128]
    float* out_pos   = out + 2097152;       // [16384][3]
    float* out_batch = out + 2146304;       // [16384]

    hipMemsetAsync(gsum, 0, 1024, stream);  // zero gsum+gsq
    front_kernel<<<400, 512, 0, stream>>>(position, features, W, bias,
                                          fps_idx, out_pos, out_batch, xnorm, Xt,
                                          hbuf, gsum, gsq);
    knn_kernel<<<512, 256, 0, stream>>>(Xt, fps_idx, xnorm, cand);
    refine_kernel<<<16384, 256, 0, stream>>>(features, fps_idx, xnorm, cand,
                                             hbuf, gsum, gsq, gamma, beta, out_feat);
}